// Round 2
// baseline (256.029 us; speedup 1.0000x reference)
//
#include <hip/hip_runtime.h>

// KnotAttention MI355X — round 9: occupancy doubling.
//
// R8 post-mortem: Y=e*V materialization (128 MB write + 128 MB read) cost
// more than the 62 MB gather it saved — fused kernel 84us, total 211us.
// REVERTED to the verified two-pass structure.
//
// R7 counters: both gather passes latency-bound (MfmaUtil 12-17%, HBM 15%,
// Occupancy 34%) — only 4 blocks/CU (LDS 40960 B) = 4 stage-bursts in
// flight. R9: NPB 32->16 halves the tile to 20480 B -> 8 blocks/CU =
// 32 waves/CU (100%). A-frags loaded in mt-halves (4 regs) to stay under
// the 64-VGPR cap of __launch_bounds__(256,8). 100000 = 6250*16: no tail.

#define N_NODES 100000
#define D 128
#define H 4
#define R 5
#define NPB 16
#define THREADS 256
#define NBLOCKS (N_NODES / NPB)   // 6250

typedef _Float16 half_t;
typedef __attribute__((ext_vector_type(8))) _Float16 f16x8;
typedef __attribute__((ext_vector_type(4))) float f32x4;

typedef const __attribute__((address_space(1))) unsigned int* gp_t;
typedef __attribute__((address_space(3))) unsigned int* lp_t;

__device__ __forceinline__ void async_copy16(const void* g, void* l) {
    __builtin_amdgcn_global_load_lds((gp_t)g, (lp_t)l, 16, 0, 0);
}

// ------------- prep: weights -> A-frags, x -> f16, zero sums_p --------------
__global__ void prep(const float* __restrict__ x,
                     const float* __restrict__ wq, const float* __restrict__ wk,
                     const float* __restrict__ wv,
                     half_t* __restrict__ xh, half_t* __restrict__ wph,
                     float* __restrict__ sums_p)
{
    const int bid = blockIdx.x;
    const int t = threadIdx.x;
    if (bid < 44) {
        const float* src = (bid < 4) ? (wq + bid * 4096)
                         : (bid < 24) ? (wk + (bid - 4) * 4096)
                                      : (wv + (bid - 24) * 4096);
#pragma unroll
        for (int i = 0; i < 16; ++i) {
            int p = t * 16 + i;
            int j = p & 7, ln = (p >> 3) & 63, f = p >> 9;
            int kt = f & 3, mt = f >> 2;
            int d = kt * 32 + (ln >> 4) * 8 + j;
            int ko = mt * 16 + (ln & 15);
            wph[bid * 4096 + p] = (half_t)src[d * 32 + ko];
        }
    } else {
        if (bid == 44) {
            for (int i = t; i < 1280; i += THREADS) sums_p[i] = 0.f;
        }
        const int total = N_NODES * D / 8;
        const int nb = gridDim.x - 44;
        for (int i = (bid - 44) * THREADS + t; i < total; i += nb * THREADS) {
            const float4* s = (const float4*)x + (size_t)i * 2;
            float4 a = s[0], b = s[1];
            f16x8 h8 = {(half_t)a.x, (half_t)a.y, (half_t)a.z, (half_t)a.w,
                        (half_t)b.x, (half_t)b.y, (half_t)b.z, (half_t)b.w};
            *((f16x8*)xh + i) = h8;
        }
    }
}

// ---------- one burst: stage all 5 slot-tiles (5 DMA instrs/wave) -----------
// tile layout: slot r at r*4096; row stride 256 B; 16-B quad kq of row stored
// at kq^(row&7) (swizzle folded into the GLOBAL address; LDS dest is
// wave-uniform base + lane*16 as HW requires).
__device__ __forceinline__ void stage_all(const half_t* __restrict__ xh,
                                          const int* __restrict__ nbr,
                                          int base, char* tile, int tid)
{
    const int w = tid >> 6;
    const int lane = tid & 63;
    const int rr = lane >> 4, c = lane & 15;
    const int row = w * 4 + rr;           // 0..15 across the 4 waves
    const int node = base + row;
    int4 a4 = ((const int4*)nbr)[node];
    int src[5] = {node, a4.x, a4.y, a4.z, a4.w};
    const int sw = ((c ^ (row & 7)) << 4);
#pragma unroll
    for (int s = 0; s < 5; ++s) {
        const char* g = (const char*)xh + (size_t)src[s] * 256 + sw;
        async_copy16(g, tile + s * 4096 + (w * 4) * 256);
    }
}

// ------------- A-frag half-load: 4 frags (one mt half), 16 VGPRs ------------
__device__ __forceinline__ void load_af4(int mid, int mt,
                                         const half_t* __restrict__ wph,
                                         int lane, f16x8 (&af)[4])
{
#pragma unroll
    for (int kt = 0; kt < 4; ++kt)
        af[kt] = *(const f16x8*)(wph + ((mid * 8 + mt * 4 + kt) * 64 + lane) * 8);
}

// -------- 32(kout) x 16(node) x 128(d) projection from LDS slot tile --------
__device__ __forceinline__ void proj16(int mid, const half_t* __restrict__ wph,
                                       const half_t* tile, int lane,
                                       f32x4 (&acc)[2])
{
    const int l15 = lane & 15, q = lane >> 4;
#pragma unroll
    for (int mt = 0; mt < 2; ++mt) {
        f16x8 af[4];
        load_af4(mid, mt, wph, lane, af);
        acc[mt] = (f32x4){0.f, 0.f, 0.f, 0.f};
#pragma unroll
        for (int kt = 0; kt < 4; ++kt) {
            int sq = (kt * 4 + q) ^ (l15 & 7);
            f16x8 b = *(const f16x8*)(tile + l15 * 128 + sq * 8);
            acc[mt] = __builtin_amdgcn_mfma_f32_16x16x32_f16(af[kt], b, acc[mt], 0, 0, 0);
        }
    }
}

// --------------------------- kernel 1: Q,K -> e, sums ------------------------
__global__ __launch_bounds__(THREADS, 8)
void knot_logits(const half_t* __restrict__ xh, const int* __restrict__ nbr,
                 const half_t* __restrict__ wph,
                 half_t* __restrict__ eh, float* __restrict__ sums_p)
{
    __shared__ __align__(16) char smem[5 * 4096];   // 20480 B -> 8 blocks/CU
    const int base = blockIdx.x * NPB;
    const int lane = threadIdx.x & 63;
    const int h = __builtin_amdgcn_readfirstlane((int)(threadIdx.x >> 6));
    const int l15 = lane & 15, q = lane >> 4;

    stage_all(xh, nbr, base, smem, threadIdx.x);
    __syncthreads();                                 // the ONLY pre-compute barrier

    f32x4 qf[2], kf[2];
    proj16(h, wph, (const half_t*)smem, lane, qf);   // Q on slot-0 tile

    half_t epk[5];
    float esum[5];
#pragma unroll
    for (int r = 0; r < R; ++r) {
        proj16(4 + h * 5 + r, wph, (const half_t*)(smem + r * 4096), lane, kf);

        float p = 0.f;
#pragma unroll
        for (int mt = 0; mt < 2; ++mt)
#pragma unroll
            for (int j = 0; j < 4; ++j)
                p += qf[mt][j] * kf[mt][j];
        p += __shfl_xor(p, 16, 64);
        p += __shfl_xor(p, 32, 64);
        float e = __expf(p * 0.17677669529663688f);
        epk[r] = (half_t)e;
        float es = e;
        es += __shfl_xor(es, 1, 64); es += __shfl_xor(es, 2, 64);
        es += __shfl_xor(es, 4, 64); es += __shfl_xor(es, 8, 64);
        esum[r] = es;    // summed over l15; q-copies identical (lane==0 atomics)
    }

    // deferred flush
#pragma unroll
    for (int r = 0; r < R; ++r) {
        if (q == 0)
            eh[(size_t)(h * 5 + r) * N_NODES + base + l15] = epk[r];
        if (lane == 0)
            atomicAdd(&sums_p[(h * 5 + r) * 64 + (blockIdx.x & 63)], esum[r]);
    }
}

// --------------------------- kernel 2: V -> Z -> out -------------------------
#define ZS 132   // zt row stride in floats (16B-aligned)
__global__ __launch_bounds__(THREADS, 8)
void knot_out(const half_t* __restrict__ xh, const int* __restrict__ nbr,
              const half_t* __restrict__ wph, const half_t* __restrict__ eh,
              const float* __restrict__ sums_p, float* __restrict__ out)
{
    __shared__ __align__(16) char smem[5 * 4096];   // tile; reused as zt
    const int base = blockIdx.x * NPB;
    const int lane = threadIdx.x & 63;
    const int h = __builtin_amdgcn_readfirstlane((int)(threadIdx.x >> 6));
    const int l15 = lane & 15, q = lane >> 4;

    stage_all(xh, nbr, base, smem, threadIdx.x);

    // register-only softmax-sum reduce (full 64-lane xor => broadcast)
    float inv[5];
#pragma unroll
    for (int r = 0; r < R; ++r) {
        float v = sums_p[(h * 5 + r) * 64 + lane];
        v += __shfl_xor(v, 1, 64);  v += __shfl_xor(v, 2, 64);
        v += __shfl_xor(v, 4, 64);  v += __shfl_xor(v, 8, 64);
        v += __shfl_xor(v, 16, 64); v += __shfl_xor(v, 32, 64);
        inv[r] = 1.0f / v;
    }
    float ev[5];
#pragma unroll
    for (int r = 0; r < R; ++r)
        ev[r] = (float)eh[(size_t)(h * 5 + r) * N_NODES + base + l15];

    __syncthreads();                                 // the ONLY pre-compute barrier

    f32x4 z[2], vf[2];
#pragma unroll
    for (int mt = 0; mt < 2; ++mt)
        z[mt] = (f32x4){0.f, 0.f, 0.f, 0.f};

#pragma unroll
    for (int r = 0; r < R; ++r) {
        proj16(24 + h * 5 + r, wph, (const half_t*)(smem + r * 4096), lane, vf);
        float w = ev[r] * inv[r];
#pragma unroll
        for (int mt = 0; mt < 2; ++mt)
#pragma unroll
            for (int j = 0; j < 4; ++j)
                z[mt][j] += w * vf[mt][j];
    }

    // ---- epilogue: node-major zt[16][ZS], float4 writes, coalesced reads ----
    __syncthreads();
    float* zt = (float*)smem;
#pragma unroll
    for (int mt = 0; mt < 2; ++mt) {
        int col = h * 32 + mt * 16 + q * 4;          // j contiguous -> f32x4
        *(f32x4*)(zt + l15 * ZS + col) = z[mt];
    }
    __syncthreads();
    {
        const int row = threadIdx.x >> 4;            // 0..15
        const int c = threadIdx.x & 15;              // 0..15
        float* dst = out + (size_t)(base + row) * D + c * 8;
        const float* srcp = zt + row * ZS + c * 8;
        *(float4*)dst       = *(const float4*)srcp;
        *(float4*)(dst + 4) = *(const float4*)(srcp + 4);
    }
}

// --------------------------------- launcher ---------------------------------
// ws (bytes): [0,5120) sums_p | [8192,+4e6) eh f16[20*N]
//             [4194304,+360448) wph | [4718592,+25.6e6) xh     ~30.3 MB
extern "C" void kernel_launch(void* const* d_in, const int* in_sizes, int n_in,
                              void* d_out, int out_size, void* d_ws, size_t ws_size,
                              hipStream_t stream)
{
    const float* x   = (const float*)d_in[0];
    const int*   nbr = (const int*)d_in[1];
    const float* w_q = (const float*)d_in[2];
    const float* w_k = (const float*)d_in[3];
    const float* w_v = (const float*)d_in[4];
    float* out = (float*)d_out;

    float*  sums_p = (float*)d_ws;
    half_t* eh     = (half_t*)((char*)d_ws + 8192);
    half_t* wph    = (half_t*)((char*)d_ws + 4194304);
    half_t* xh     = (half_t*)((char*)d_ws + 4718592);

    prep<<<44 + 2048, THREADS, 0, stream>>>(x, w_q, w_k, w_v, xh, wph, sums_p);
    knot_logits<<<NBLOCKS, THREADS, 0, stream>>>(xh, nbr, wph, eh, sums_p);
    knot_out<<<NBLOCKS, THREADS, 0, stream>>>(xh, nbr, wph, eh, sums_p, out);
}